// Round 11
// baseline (184.124 us; speedup 1.0000x reference)
//
#include <hip/hip_runtime.h>
#include <hip/hip_bf16.h>
#include <stdint.h>

#define B_   256
#define C_   10
#define S_   500
#define H_   256
#define OUT_ 500
#define M_   (B_ * S_)   // 128000
#define FCK  (S_ * H_)   // 128000
#define ND   16          // Chebyshev nodes (degree 15)
#define KE   24000       // extended K: [hi|hi|lo] x 500*16
#define PI_F 3.14159265358979f

typedef __attribute__((ext_vector_type(8))) short s16x8;   // 8 bf16
typedef __attribute__((ext_vector_type(4))) float f32x4;

__device__ __forceinline__ unsigned short f2bf(float f) {
  union { float f; unsigned u; } v; v.f = f;
  unsigned r = v.u + 0x7fffu + ((v.u >> 16) & 1u);   // RNE
  return (unsigned short)(r >> 16);
}
__device__ __forceinline__ float bf2f(unsigned short u) {
  union { unsigned u; float f; } v; v.u = ((unsigned)u) << 16; return v.f;
}
__device__ __forceinline__ float sigf(float x) { return 1.0f / (1.0f + __expf(-x)); }
__device__ __forceinline__ float tanh_f(float x) { return 1.0f - 2.0f / (__expf(2.0f * x) + 1.0f); }

// pack 8 f32 -> 8 bf16 via v_cvt_pk_bf16_f32 (S0 low 16, S1 high 16; RNE)
__device__ __forceinline__ s16x8 pack_bf16x8(f32x4 a, f32x4 b) {
  union { s16x8 v; unsigned u[4]; } r;
  asm("v_cvt_pk_bf16_f32 %0, %1, %2" : "=v"(r.u[0]) : "v"(a[0]), "v"(a[1]));
  asm("v_cvt_pk_bf16_f32 %0, %1, %2" : "=v"(r.u[1]) : "v"(a[2]), "v"(a[3]));
  asm("v_cvt_pk_bf16_f32 %0, %1, %2" : "=v"(r.u[2]) : "v"(b[0]), "v"(b[1]));
  asm("v_cvt_pk_bf16_f32 %0, %1, %2" : "=v"(r.u[3]) : "v"(b[2]), "v"(b[3]));
  return r.v;
}

// split 8 f32 into bf16 hi + bf16 lo (lo = x - f32(hi), exact by Sterbenz)
__device__ __forceinline__ void split8(f32x4 a, f32x4 b, s16x8* hi, s16x8* lo) {
  union { s16x8 v; unsigned u[4]; } h;
  h.v = pack_bf16x8(a, b);
  union { unsigned u; float f; } c;
  f32x4 ra, rb;
  c.u = h.u[0] << 16;          ra[0] = c.f;
  c.u = h.u[0] & 0xffff0000u;  ra[1] = c.f;
  c.u = h.u[1] << 16;          ra[2] = c.f;
  c.u = h.u[1] & 0xffff0000u;  ra[3] = c.f;
  c.u = h.u[2] << 16;          rb[0] = c.f;
  c.u = h.u[2] & 0xffff0000u;  rb[1] = c.f;
  c.u = h.u[3] << 16;          rb[2] = c.f;
  c.u = h.u[3] & 0xffff0000u;  rb[3] = c.f;
  *hi = h.v;
  *lo = pack_bf16x8(a - ra, b - rb);
}

// ---- conv center tap + relu: y[b*S+s] ----
__global__ void k_conv(const float* __restrict__ x, const float* __restrict__ cw,
                       const float* __restrict__ cb, float* __restrict__ y) {
  int n = blockIdx.x * 256 + threadIdx.x;            // 128000 exact
  int b = n / S_, s = n - b * S_;
  const float* xp = x + (size_t)b * C_ * S_ + s;
  float acc = cb[0];
#pragma unroll
  for (int c = 0; c < C_; ++c) acc += xp[c * S_] * cw[c * 5 + 2];
  y[n] = fmaxf(acc, 0.0f);
}

// ---- h0 at the 16 Chebyshev nodes (pure f32) ----
__global__ void k_h0n(const float* __restrict__ w0, const float* __restrict__ bi0,
                      const float* __restrict__ bh0, float* __restrict__ h0n) {
  int tid = blockIdx.x * 256 + threadIdx.x;          // 4096
  int j = tid >> 8, k = tid & 255;
  float th = PI_F * ((float)j + 0.5f) / 16.0f;
  float yv = (cosf(th) + 1.0f) * 0.5f;               // node in [0,1]
  float gi = yv * w0[k] + bi0[k] + bh0[k];
  float gg = yv * w0[512 + k] + bi0[512 + k] + bh0[512 + k];
  float go = yv * w0[768 + k] + bi0[768 + k] + bh0[768 + k];
  float c = sigf(gi) * tanh_f(gg);
  h0n[tid] = sigf(go) * tanh_f(c);
}

// ---- h1 at the nodes (f32 dots against original f32 w_ih1) ----
__global__ void k_h1n(const float* __restrict__ h0n, const float* __restrict__ w1,
                      const float* __restrict__ b1i, const float* __restrict__ b1h,
                      float* __restrict__ h1n) {
  int tid = blockIdx.x * 256 + threadIdx.x;          // 4096
  int j = tid >> 8, col = tid & 255;
  const float* h  = h0n + j * 256;
  const float* wi = w1 + (size_t)col * 256;
  const float* wg = w1 + (size_t)(512 + col) * 256;
  const float* wo = w1 + (size_t)(768 + col) * 256;
  float gi = b1i[col] + b1h[col];
  float gg = b1i[512 + col] + b1h[512 + col];
  float go = b1i[768 + col] + b1h[768 + col];
  for (int k = 0; k < 256; ++k) {
    float hv = h[k];
    gi += hv * wi[k]; gg += hv * wg[k]; go += hv * wo[k];
  }
  float c = sigf(gi) * tanh_f(gg);
  h1n[tid] = sigf(go) * tanh_f(c);
}

// ---- Chebyshev coefficients via DCT-II; split to bf16 hi/lo [16][256] ----
__global__ void k_cheb(const float* __restrict__ h1n,
                       unsigned short* __restrict__ ch, unsigned short* __restrict__ cl) {
  int tid = blockIdx.x * 256 + threadIdx.x;          // 4096
  int d = tid >> 8, k = tid & 255;
  float s = 0.f;
  for (int j = 0; j < 16; ++j)
    s += h1n[j * 256 + k] * cosf(PI_F * (float)d * ((float)j + 0.5f) / 16.0f);
  float c = s * ((d == 0) ? (1.0f / 16.0f) : (2.0f / 16.0f));
  unsigned short h = f2bf(c);
  ch[tid] = h;
  cl[tid] = f2bf(c - bf2f(h));
}

// ---- P-gen: A'[b][s*16+d] = [T_hi | T_hi | T_lo], T_d = Cheb(2*min(y,1)-1) ----
__global__ void k_pgen(const float* __restrict__ y, unsigned short* __restrict__ Ps) {
  int n = blockIdx.x * 256 + threadIdx.x;            // 128000 exact
  float xv = 2.0f * fminf(y[n], 1.0f) - 1.0f;
  float T[16];
  T[0] = 1.0f; T[1] = xv;
#pragma unroll
  for (int d = 2; d < 16; ++d) T[d] = 2.0f * xv * T[d - 1] - T[d - 2];
  f32x4 t0 = {T[0], T[1], T[2], T[3]},   t1 = {T[4], T[5], T[6], T[7]};
  f32x4 t2 = {T[8], T[9], T[10], T[11]}, t3 = {T[12], T[13], T[14], T[15]};
  s16x8 h0v, l0v, h1v, l1v;
  split8(t0, t1, &h0v, &l0v);
  split8(t2, t3, &h1v, &l1v);
  int bb = n / S_, ss = n - bb * S_;
  unsigned short* base = Ps + (size_t)bb * KE + ss * 16;
  *(s16x8*)(base)         = h0v;  *(s16x8*)(base + 8)         = h1v;
  *(s16x8*)(base + 8000)  = h0v;  *(s16x8*)(base + 8008)      = h1v;
  *(s16x8*)(base + 16000) = l0v;  *(s16x8*)(base + 16008)     = l1v;
}

// ---- Q: stream fc_w once. Q[os][d] = sum_k w[os][k]*c_d[k], split-bf16 MFMA.
// wave = one 16-row strip of fc_w viewed [250000][256]; no LDS, no barriers.
// Epilogue writes B' = [Q_hi | Q_lo | Q_hi] bf16 [500][24000].
__global__ __launch_bounds__(256) void k_q(
    const float* __restrict__ W, const unsigned short* __restrict__ ch,
    const unsigned short* __restrict__ cl, unsigned short* __restrict__ Qs) {
  int wv = blockIdx.x * 4 + (threadIdx.x >> 6);      // strip id
  if (wv >= 15625) return;                           // 250000/16 exact
  const int lane = threadIdx.x & 63;
  const int row0 = wv * 16;
  const int m = lane & 15, kq = (lane >> 4) * 8;
  const float* wp = W + (size_t)(row0 + m) * 256 + kq;
  const unsigned short* cph = ch + m * 256 + kq;     // B-frag: d = lane&15
  const unsigned short* cpl = cl + m * 256 + kq;
  s16x8 cbh[8], cbl[8];
#pragma unroll
  for (int st = 0; st < 8; ++st) {
    cbh[st] = *(const s16x8*)(cph + st * 32);
    cbl[st] = *(const s16x8*)(cpl + st * 32);
  }
  f32x4 acc = {0.f, 0.f, 0.f, 0.f};
#pragma unroll
  for (int st = 0; st < 8; ++st) {
    f32x4 wa = *(const f32x4*)(wp + st * 32);
    f32x4 wb = *(const f32x4*)(wp + st * 32 + 4);
    s16x8 hi, lo;
    split8(wa, wb, &hi, &lo);
    acc = __builtin_amdgcn_mfma_f32_16x16x32_bf16(hi, cbh[st], acc, 0, 0, 0);
    acc = __builtin_amdgcn_mfma_f32_16x16x32_bf16(hi, cbl[st], acc, 0, 0, 0);
    acc = __builtin_amdgcn_mfma_f32_16x16x32_bf16(lo, cbh[st], acc, 0, 0, 0);
  }
  const int d = lane & 15;
#pragma unroll
  for (int r = 0; r < 4; ++r) {
    int os = row0 + (lane >> 4) * 4 + r;
    int o = os / 500, s = os - o * 500;
    float q = acc[r];
    unsigned short h = f2bf(q);
    unsigned short l = f2bf(q - bf2f(h));
    unsigned short* qb = Qs + (size_t)o * KE + s * 16 + d;
    qb[0] = h; qb[8000] = l; qb[16000] = h;
  }
}

// ---- final GEMM: pfc[ks] += A'(256xKE) . B'(500xKE)^T over ks-chunk of 960 ----
// grid 400 = ks(25) x bm(2) x bo(8); 4 waves, no LDS, no barriers.
__global__ __launch_bounds__(256) void k_fc(
    const unsigned short* __restrict__ Ps, const unsigned short* __restrict__ Qs,
    float* __restrict__ pfc) {
  const int blk = blockIdx.x;
  const int ks = blk % 25, rest = blk / 25;
  const int bm = rest & 1, bo = rest >> 1;
  const int lane = threadIdx.x & 63, nw = threadIdx.x >> 6;
  const int kbase = ks * 960;
  const int ob = bo * 64 + nw * 16 + (lane & 15);
  const int obc = ob > 499 ? 499 : ob;
  const unsigned short* bp = Qs + (size_t)obc * KE + kbase + (lane >> 4) * 8;
  const unsigned short* ap = Ps + (size_t)(bm * 128 + (lane & 15)) * KE + kbase + (lane >> 4) * 8;
  f32x4 acc[8] = {};
#pragma unroll 3
  for (int st = 0; st < 30; ++st) {
    s16x8 bf = *(const s16x8*)(bp + st * 32);
#pragma unroll
    for (int mf = 0; mf < 8; ++mf) {
      s16x8 af = *(const s16x8*)(ap + (size_t)mf * 16 * KE + st * 32);
      acc[mf] = __builtin_amdgcn_mfma_f32_16x16x32_bf16(af, bf, acc[mf], 0, 0, 0);
    }
  }
  const int col = bo * 64 + nw * 16 + (lane & 15);
  if (col < OUT_) {
    float* pp = pfc + (size_t)ks * 128000;
#pragma unroll
    for (int mf = 0; mf < 8; ++mf) {
#pragma unroll
      for (int r = 0; r < 4; ++r) {
        int row = bm * 128 + mf * 16 + (lane >> 4) * 4 + r;
        pp[row * OUT_ + col] = acc[mf][r];
      }
    }
  }
}

// ---- reduce: out[i] = fc_b[i%500] + sum_ks pfc[ks][i] ----
__global__ void k_red2(const float* __restrict__ pfc, const float* __restrict__ fcb,
                       float* __restrict__ out) {
  int i = blockIdx.x * 256 + threadIdx.x;            // 128000 exact
  int o = i % OUT_;
  float s = fcb[o];
#pragma unroll 5
  for (int ks = 0; ks < 25; ++ks) s += pfc[(size_t)ks * 128000 + i];
  out[i] = s;
}

extern "C" void kernel_launch(void* const* d_in, const int* in_sizes, int n_in,
                              void* d_out, int out_size, void* d_ws, size_t ws_size,
                              hipStream_t stream) {
  const float* x      = (const float*)d_in[0];
  const float* conv_w = (const float*)d_in[1];
  const float* conv_b = (const float*)d_in[2];
  const float* w_ih0  = (const float*)d_in[3];
  const float* b_ih0  = (const float*)d_in[4];
  const float* b_hh0  = (const float*)d_in[5];
  const float* w_ih1  = (const float*)d_in[6];
  const float* b_ih1  = (const float*)d_in[7];
  const float* b_hh1  = (const float*)d_in[8];
  const float* fc_w   = (const float*)d_in[9];
  const float* fc_b   = (const float*)d_in[10];
  float* out = (float*)d_out;

  char* ws = (char*)d_ws;
  float* y            = (float*)ws;                        // 512,000 B
  float* h0n          = (float*)(ws + 524288);             // 16,384 B
  float* h1n          = (float*)(ws + 540672);             // 16,384 B
  unsigned short* ch  = (unsigned short*)(ws + 557056);    // 8,192 B
  unsigned short* cl  = (unsigned short*)(ws + 565248);    // 8,192 B
  unsigned short* Ps  = (unsigned short*)(ws + 1048576);   // 12,288,000 B
  unsigned short* Qs  = (unsigned short*)(ws + 14680064);  // 24,000,000 B
  float* pfc          = (float*)(ws + 41943040);           // 12,800,000 B

  k_conv<<<500, 256, 0, stream>>>(x, conv_w, conv_b, y);
  k_h0n<<<16, 256, 0, stream>>>(w_ih0, b_ih0, b_hh0, h0n);
  k_h1n<<<16, 256, 0, stream>>>(h0n, w_ih1, b_ih1, b_hh1, h1n);
  k_cheb<<<16, 256, 0, stream>>>(h1n, ch, cl);
  k_pgen<<<500, 256, 0, stream>>>(y, Ps);
  k_q<<<3907, 256, 0, stream>>>(fc_w, ch, cl, Qs);
  k_fc<<<400, 256, 0, stream>>>(Ps, Qs, pfc);
  k_red2<<<500, 256, 0, stream>>>(pfc, fc_b, out);
}

// Round 12
// 180.177 us; speedup vs baseline: 1.0219x; 1.0219x over previous
//
#include <hip/hip_runtime.h>
#include <hip/hip_bf16.h>
#include <stdint.h>

#define B_   256
#define C_   10
#define S_   500
#define H_   256
#define OUT_ 500
#define M_   (B_ * S_)   // 128000
#define FCK  (S_ * H_)   // 128000
#define ND   16          // Chebyshev nodes (degree 15)
#define KE   24000       // extended K: [hi|hi|lo] x 500*16
#define PI_F 3.14159265358979f

typedef __attribute__((ext_vector_type(8))) short s16x8;   // 8 bf16
typedef __attribute__((ext_vector_type(4))) float f32x4;

__device__ __forceinline__ unsigned short f2bf(float f) {
  union { float f; unsigned u; } v; v.f = f;
  unsigned r = v.u + 0x7fffu + ((v.u >> 16) & 1u);   // RNE
  return (unsigned short)(r >> 16);
}
__device__ __forceinline__ float bf2f(unsigned short u) {
  union { unsigned u; float f; } v; v.u = ((unsigned)u) << 16; return v.f;
}
__device__ __forceinline__ float sigf(float x) { return 1.0f / (1.0f + __expf(-x)); }
__device__ __forceinline__ float tanh_f(float x) { return 1.0f - 2.0f / (__expf(2.0f * x) + 1.0f); }

__device__ __forceinline__ void gload16(const void* g, void* l) {
  __builtin_amdgcn_global_load_lds((const __attribute__((address_space(1))) void*)g,
                                   (__attribute__((address_space(3))) void*)l, 16, 0, 0);
}

// pack 8 f32 -> 8 bf16 via v_cvt_pk_bf16_f32 (S0 low 16, S1 high 16; RNE)
__device__ __forceinline__ s16x8 pack_bf16x8(f32x4 a, f32x4 b) {
  union { s16x8 v; unsigned u[4]; } r;
  asm("v_cvt_pk_bf16_f32 %0, %1, %2" : "=v"(r.u[0]) : "v"(a[0]), "v"(a[1]));
  asm("v_cvt_pk_bf16_f32 %0, %1, %2" : "=v"(r.u[1]) : "v"(a[2]), "v"(a[3]));
  asm("v_cvt_pk_bf16_f32 %0, %1, %2" : "=v"(r.u[2]) : "v"(b[0]), "v"(b[1]));
  asm("v_cvt_pk_bf16_f32 %0, %1, %2" : "=v"(r.u[3]) : "v"(b[2]), "v"(b[3]));
  return r.v;
}

// split 8 f32 into bf16 hi + bf16 lo (lo = x - f32(hi))
__device__ __forceinline__ void split8(f32x4 a, f32x4 b, s16x8* hi, s16x8* lo) {
  union { s16x8 v; unsigned u[4]; } h;
  h.v = pack_bf16x8(a, b);
  union { unsigned u; float f; } c;
  f32x4 ra, rb;
  c.u = h.u[0] << 16;          ra[0] = c.f;
  c.u = h.u[0] & 0xffff0000u;  ra[1] = c.f;
  c.u = h.u[1] << 16;          ra[2] = c.f;
  c.u = h.u[1] & 0xffff0000u;  ra[3] = c.f;
  c.u = h.u[2] << 16;          rb[0] = c.f;
  c.u = h.u[2] & 0xffff0000u;  rb[1] = c.f;
  c.u = h.u[3] << 16;          rb[2] = c.f;
  c.u = h.u[3] & 0xffff0000u;  rb[3] = c.f;
  *hi = h.v;
  *lo = pack_bf16x8(a - ra, b - rb);
}

// ---- conv center tap + relu: y[b*S+s] ----
__global__ void k_conv(const float* __restrict__ x, const float* __restrict__ cw,
                       const float* __restrict__ cb, float* __restrict__ y) {
  int n = blockIdx.x * 256 + threadIdx.x;            // 128000 exact
  int b = n / S_, s = n - b * S_;
  const float* xp = x + (size_t)b * C_ * S_ + s;
  float acc = cb[0];
#pragma unroll
  for (int c = 0; c < C_; ++c) acc += xp[c * S_] * cw[c * 5 + 2];
  y[n] = fmaxf(acc, 0.0f);
}

// ---- h0 at the 16 Chebyshev nodes (pure f32) ----
__global__ void k_h0n(const float* __restrict__ w0, const float* __restrict__ bi0,
                      const float* __restrict__ bh0, float* __restrict__ h0n) {
  int tid = blockIdx.x * 256 + threadIdx.x;          // 4096
  int j = tid >> 8, k = tid & 255;
  float th = PI_F * ((float)j + 0.5f) / 16.0f;
  float yv = (cosf(th) + 1.0f) * 0.5f;               // node in [0,1]
  float gi = yv * w0[k] + bi0[k] + bh0[k];
  float gg = yv * w0[512 + k] + bi0[512 + k] + bh0[512 + k];
  float go = yv * w0[768 + k] + bi0[768 + k] + bh0[768 + k];
  float c = sigf(gi) * tanh_f(gg);
  h0n[tid] = sigf(go) * tanh_f(c);
}

// ---- h1 at the nodes (f32 dots against original f32 w_ih1) ----
__global__ void k_h1n(const float* __restrict__ h0n, const float* __restrict__ w1,
                      const float* __restrict__ b1i, const float* __restrict__ b1h,
                      float* __restrict__ h1n) {
  int tid = blockIdx.x * 256 + threadIdx.x;          // 4096
  int j = tid >> 8, col = tid & 255;
  const float* h  = h0n + j * 256;
  const float* wi = w1 + (size_t)col * 256;
  const float* wg = w1 + (size_t)(512 + col) * 256;
  const float* wo = w1 + (size_t)(768 + col) * 256;
  float gi = b1i[col] + b1h[col];
  float gg = b1i[512 + col] + b1h[512 + col];
  float go = b1i[768 + col] + b1h[768 + col];
  for (int k = 0; k < 256; ++k) {
    float hv = h[k];
    gi += hv * wi[k]; gg += hv * wg[k]; go += hv * wo[k];
  }
  float c = sigf(gi) * tanh_f(gg);
  h1n[tid] = sigf(go) * tanh_f(c);
}

// ---- Chebyshev coefficients via DCT-II; split to bf16 hi/lo [16][256] ----
__global__ void k_cheb(const float* __restrict__ h1n,
                       unsigned short* __restrict__ ch, unsigned short* __restrict__ cl) {
  int tid = blockIdx.x * 256 + threadIdx.x;          // 4096
  int d = tid >> 8, k = tid & 255;
  float s = 0.f;
  for (int j = 0; j < 16; ++j)
    s += h1n[j * 256 + k] * cosf(PI_F * (float)d * ((float)j + 0.5f) / 16.0f);
  float c = s * ((d == 0) ? (1.0f / 16.0f) : (2.0f / 16.0f));
  unsigned short h = f2bf(c);
  ch[tid] = h;
  cl[tid] = f2bf(c - bf2f(h));
}

// ---- P-gen: A'[b][s*16+d] = [T_hi | T_hi | T_lo], T_d = Cheb(2*min(y,1)-1) ----
__global__ void k_pgen(const float* __restrict__ y, unsigned short* __restrict__ Ps) {
  int n = blockIdx.x * 256 + threadIdx.x;            // 128000 exact
  float xv = 2.0f * fminf(y[n], 1.0f) - 1.0f;
  float T[16];
  T[0] = 1.0f; T[1] = xv;
#pragma unroll
  for (int d = 2; d < 16; ++d) T[d] = 2.0f * xv * T[d - 1] - T[d - 2];
  f32x4 t0 = {T[0], T[1], T[2], T[3]},   t1 = {T[4], T[5], T[6], T[7]};
  f32x4 t2 = {T[8], T[9], T[10], T[11]}, t3 = {T[12], T[13], T[14], T[15]};
  s16x8 h0v, l0v, h1v, l1v;
  split8(t0, t1, &h0v, &l0v);
  split8(t2, t3, &h1v, &l1v);
  int bb = n / S_, ss = n - bb * S_;
  unsigned short* base = Ps + (size_t)bb * KE + ss * 16;
  *(s16x8*)(base)         = h0v;  *(s16x8*)(base + 8)         = h1v;
  *(s16x8*)(base + 8000)  = h0v;  *(s16x8*)(base + 8008)      = h1v;
  *(s16x8*)(base + 16000) = l0v;  *(s16x8*)(base + 16008)     = l1v;
}

// ---- Q v2: dense-stage 64 rows x 256 f32 of fc_w into LDS (source-XOR
// swizzle), then split-bf16 MFMA from LDS. One barrier, single-shot block.
// Writes B' = [Q_hi | Q_lo | Q_hi] bf16 [500][24000].
__global__ __launch_bounds__(256) void k_q(
    const float* __restrict__ W, const unsigned short* __restrict__ ch,
    const unsigned short* __restrict__ cl, unsigned short* __restrict__ Qs) {
  __shared__ __align__(16) float Ws[64 * 256];       // 64 KB
  const int t = threadIdx.x, lane = t & 63, w = t >> 6;
  const int row0 = blockIdx.x * 64;                  // grid 3907; last block partial

  // stage: 4096 chunks of 16B, linear LDS dest, swizzled global source.
  // LDS slot (r, s) holds global chunk (r, s ^ (r&15)).
#pragma unroll
  for (int it = 0; it < 16; ++it) {
    int q = it * 256 + t;
    int r = q >> 6, sc = (q & 63) ^ (r & 15);
    int rg = row0 + r; if (rg > 249999) rg = 249999;
    gload16(W + (size_t)rg * 256 + (sc << 2), (void*)&Ws[q * 4]);
  }

  // B-fragments: d = lane&15, k-chunk = (lane>>4)*8
  const int m = lane & 15, kq = (lane >> 4) * 8;
  const unsigned short* cph = ch + m * 256 + kq;
  const unsigned short* cpl = cl + m * 256 + kq;
  s16x8 cbh[8], cbl[8];
#pragma unroll
  for (int st = 0; st < 8; ++st) {
    cbh[st] = *(const s16x8*)(cph + st * 32);
    cbl[st] = *(const s16x8*)(cpl + st * 32);
  }
  __syncthreads();                                   // drains gload_lds

  const int ra = w * 16 + m;                         // LDS row of this lane's A-frag
  f32x4 acc = {0.f, 0.f, 0.f, 0.f};
#pragma unroll
  for (int st = 0; st < 8; ++st) {
    const int gc0 = st * 8 + (lane >> 4) * 2;        // 16B-chunk index (0..63)
    f32x4 wa = *(const f32x4*)&Ws[(ra * 64 + (gc0 ^ (ra & 15))) * 4];
    f32x4 wb = *(const f32x4*)&Ws[(ra * 64 + ((gc0 + 1) ^ (ra & 15))) * 4];
    s16x8 hi, lo;
    split8(wa, wb, &hi, &lo);
    acc = __builtin_amdgcn_mfma_f32_16x16x32_bf16(hi, cbh[st], acc, 0, 0, 0);
    acc = __builtin_amdgcn_mfma_f32_16x16x32_bf16(hi, cbl[st], acc, 0, 0, 0);
    acc = __builtin_amdgcn_mfma_f32_16x16x32_bf16(lo, cbh[st], acc, 0, 0, 0);
  }

  const int d = lane & 15;
#pragma unroll
  for (int r = 0; r < 4; ++r) {
    int os = row0 + w * 16 + (lane >> 4) * 4 + r;
    if (os < 250000) {
      int o = os / 500, s = os - o * 500;
      float q = acc[r];
      unsigned short h = f2bf(q);
      unsigned short l = f2bf(q - bf2f(h));
      unsigned short* qb = Qs + (size_t)o * KE + s * 16 + d;
      qb[0] = h; qb[8000] = l; qb[16000] = h;
    }
  }
}

// ---- final GEMM: pfc[ks] += A'(256xKE) . B'(500xKE)^T over ks-chunk of 960 ----
// grid 400 = ks(25) x bm(2) x bo(8); 4 waves, no LDS, no barriers.
__global__ __launch_bounds__(256) void k_fc(
    const unsigned short* __restrict__ Ps, const unsigned short* __restrict__ Qs,
    float* __restrict__ pfc) {
  const int blk = blockIdx.x;
  const int ks = blk % 25, rest = blk / 25;
  const int bm = rest & 1, bo = rest >> 1;
  const int lane = threadIdx.x & 63, nw = threadIdx.x >> 6;
  const int kbase = ks * 960;
  const int ob = bo * 64 + nw * 16 + (lane & 15);
  const int obc = ob > 499 ? 499 : ob;
  const unsigned short* bp = Qs + (size_t)obc * KE + kbase + (lane >> 4) * 8;
  const unsigned short* ap = Ps + (size_t)(bm * 128 + (lane & 15)) * KE + kbase + (lane >> 4) * 8;
  f32x4 acc[8] = {};
#pragma unroll 3
  for (int st = 0; st < 30; ++st) {
    s16x8 bf = *(const s16x8*)(bp + st * 32);
#pragma unroll
    for (int mf = 0; mf < 8; ++mf) {
      s16x8 af = *(const s16x8*)(ap + (size_t)mf * 16 * KE + st * 32);
      acc[mf] = __builtin_amdgcn_mfma_f32_16x16x32_bf16(af, bf, acc[mf], 0, 0, 0);
    }
  }
  const int col = bo * 64 + nw * 16 + (lane & 15);
  if (col < OUT_) {
    float* pp = pfc + (size_t)ks * 128000;
#pragma unroll
    for (int mf = 0; mf < 8; ++mf) {
#pragma unroll
      for (int r = 0; r < 4; ++r) {
        int row = bm * 128 + mf * 16 + (lane >> 4) * 4 + r;
        pp[row * OUT_ + col] = acc[mf][r];
      }
    }
  }
}

// ---- reduce: out[i] = fc_b[i%500] + sum_ks pfc[ks][i] ----
__global__ void k_red2(const float* __restrict__ pfc, const float* __restrict__ fcb,
                       float* __restrict__ out) {
  int i = blockIdx.x * 256 + threadIdx.x;            // 128000 exact
  int o = i % OUT_;
  float s = fcb[o];
#pragma unroll 5
  for (int ks = 0; ks < 25; ++ks) s += pfc[(size_t)ks * 128000 + i];
  out[i] = s;
}

extern "C" void kernel_launch(void* const* d_in, const int* in_sizes, int n_in,
                              void* d_out, int out_size, void* d_ws, size_t ws_size,
                              hipStream_t stream) {
  const float* x      = (const float*)d_in[0];
  const float* conv_w = (const float*)d_in[1];
  const float* conv_b = (const float*)d_in[2];
  const float* w_ih0  = (const float*)d_in[3];
  const float* b_ih0  = (const float*)d_in[4];
  const float* b_hh0  = (const float*)d_in[5];
  const float* w_ih1  = (const float*)d_in[6];
  const float* b_ih1  = (const float*)d_in[7];
  const float* b_hh1  = (const float*)d_in[8];
  const float* fc_w   = (const float*)d_in[9];
  const float* fc_b   = (const float*)d_in[10];
  float* out = (float*)d_out;

  char* ws = (char*)d_ws;
  float* y            = (float*)ws;                        // 512,000 B
  float* h0n          = (float*)(ws + 524288);             // 16,384 B
  float* h1n          = (float*)(ws + 540672);             // 16,384 B
  unsigned short* ch  = (unsigned short*)(ws + 557056);    // 8,192 B
  unsigned short* cl  = (unsigned short*)(ws + 565248);    // 8,192 B
  unsigned short* Ps  = (unsigned short*)(ws + 1048576);   // 12,288,000 B
  unsigned short* Qs  = (unsigned short*)(ws + 14680064);  // 24,000,000 B
  float* pfc          = (float*)(ws + 41943040);           // 12,800,000 B

  k_conv<<<500, 256, 0, stream>>>(x, conv_w, conv_b, y);
  k_h0n<<<16, 256, 0, stream>>>(w_ih0, b_ih0, b_hh0, h0n);
  k_h1n<<<16, 256, 0, stream>>>(h0n, w_ih1, b_ih1, b_hh1, h1n);
  k_cheb<<<16, 256, 0, stream>>>(h1n, ch, cl);
  k_pgen<<<500, 256, 0, stream>>>(y, Ps);
  k_q<<<3907, 256, 0, stream>>>(fc_w, ch, cl, Qs);
  k_fc<<<400, 256, 0, stream>>>(Ps, Qs, pfc);
  k_red2<<<500, 256, 0, stream>>>(pfc, fc_b, out);
}

// Round 13
// 170.953 us; speedup vs baseline: 1.0770x; 1.0540x over previous
//
#include <hip/hip_runtime.h>
#include <hip/hip_bf16.h>
#include <stdint.h>

#define B_   256
#define C_   10
#define S_   500
#define H_   256
#define OUT_ 500
#define M_   (B_ * S_)   // 128000
#define FCK  (S_ * H_)   // 128000
#define ND   16          // Chebyshev nodes (degree 15)
#define KE   24000       // extended K: [hi|hi|lo] x 500*16
#define PI_F 3.14159265358979f

typedef __attribute__((ext_vector_type(8))) short s16x8;   // 8 bf16
typedef __attribute__((ext_vector_type(4))) float f32x4;

__device__ __forceinline__ unsigned short f2bf(float f) {
  union { float f; unsigned u; } v; v.f = f;
  unsigned r = v.u + 0x7fffu + ((v.u >> 16) & 1u);   // RNE
  return (unsigned short)(r >> 16);
}
__device__ __forceinline__ float bf2f(unsigned short u) {
  union { unsigned u; float f; } v; v.u = ((unsigned)u) << 16; return v.f;
}
__device__ __forceinline__ float sigf(float x) { return 1.0f / (1.0f + __expf(-x)); }
__device__ __forceinline__ float tanh_f(float x) { return 1.0f - 2.0f / (__expf(2.0f * x) + 1.0f); }

// pack 8 f32 -> 8 bf16 via v_cvt_pk_bf16_f32 (S0 low 16, S1 high 16; RNE)
__device__ __forceinline__ s16x8 pack_bf16x8(f32x4 a, f32x4 b) {
  union { s16x8 v; unsigned u[4]; } r;
  asm("v_cvt_pk_bf16_f32 %0, %1, %2" : "=v"(r.u[0]) : "v"(a[0]), "v"(a[1]));
  asm("v_cvt_pk_bf16_f32 %0, %1, %2" : "=v"(r.u[1]) : "v"(a[2]), "v"(a[3]));
  asm("v_cvt_pk_bf16_f32 %0, %1, %2" : "=v"(r.u[2]) : "v"(b[0]), "v"(b[1]));
  asm("v_cvt_pk_bf16_f32 %0, %1, %2" : "=v"(r.u[3]) : "v"(b[2]), "v"(b[3]));
  return r.v;
}

// split 8 f32 into bf16 hi + bf16 lo (lo = x - f32(hi))
__device__ __forceinline__ void split8(f32x4 a, f32x4 b, s16x8* hi, s16x8* lo) {
  union { s16x8 v; unsigned u[4]; } h;
  h.v = pack_bf16x8(a, b);
  union { unsigned u; float f; } c;
  f32x4 ra, rb;
  c.u = h.u[0] << 16;          ra[0] = c.f;
  c.u = h.u[0] & 0xffff0000u;  ra[1] = c.f;
  c.u = h.u[1] << 16;          ra[2] = c.f;
  c.u = h.u[1] & 0xffff0000u;  ra[3] = c.f;
  c.u = h.u[2] << 16;          rb[0] = c.f;
  c.u = h.u[2] & 0xffff0000u;  rb[1] = c.f;
  c.u = h.u[3] << 16;          rb[2] = c.f;
  c.u = h.u[3] & 0xffff0000u;  rb[3] = c.f;
  *hi = h.v;
  *lo = pack_bf16x8(a - ra, b - rb);
}

// ---- conv center tap + relu: y[b*S+s] ----
__global__ void k_conv(const float* __restrict__ x, const float* __restrict__ cw,
                       const float* __restrict__ cb, float* __restrict__ y) {
  int n = blockIdx.x * 256 + threadIdx.x;            // 128000 exact
  int b = n / S_, s = n - b * S_;
  const float* xp = x + (size_t)b * C_ * S_ + s;
  float acc = cb[0];
#pragma unroll
  for (int c = 0; c < C_; ++c) acc += xp[c * S_] * cw[c * 5 + 2];
  y[n] = fmaxf(acc, 0.0f);
}

// ---- h0 at the 16 Chebyshev nodes (pure f32) ----
__global__ void k_h0n(const float* __restrict__ w0, const float* __restrict__ bi0,
                      const float* __restrict__ bh0, float* __restrict__ h0n) {
  int tid = blockIdx.x * 256 + threadIdx.x;          // 4096
  int j = tid >> 8, k = tid & 255;
  float th = PI_F * ((float)j + 0.5f) / 16.0f;
  float yv = (cosf(th) + 1.0f) * 0.5f;               // node in [0,1]
  float gi = yv * w0[k] + bi0[k] + bh0[k];
  float gg = yv * w0[512 + k] + bi0[512 + k] + bh0[512 + k];
  float go = yv * w0[768 + k] + bi0[768 + k] + bh0[768 + k];
  float c = sigf(gi) * tanh_f(gg);
  h0n[tid] = sigf(go) * tanh_f(c);
}

// ---- h1 at the nodes (f32 dots against original f32 w_ih1) ----
__global__ void k_h1n(const float* __restrict__ h0n, const float* __restrict__ w1,
                      const float* __restrict__ b1i, const float* __restrict__ b1h,
                      float* __restrict__ h1n) {
  int tid = blockIdx.x * 256 + threadIdx.x;          // 4096
  int j = tid >> 8, col = tid & 255;
  const float* h  = h0n + j * 256;
  const float* wi = w1 + (size_t)col * 256;
  const float* wg = w1 + (size_t)(512 + col) * 256;
  const float* wo = w1 + (size_t)(768 + col) * 256;
  float gi = b1i[col] + b1h[col];
  float gg = b1i[512 + col] + b1h[512 + col];
  float go = b1i[768 + col] + b1h[768 + col];
  for (int k = 0; k < 256; ++k) {
    float hv = h[k];
    gi += hv * wi[k]; gg += hv * wg[k]; go += hv * wo[k];
  }
  float c = sigf(gi) * tanh_f(gg);
  h1n[tid] = sigf(go) * tanh_f(c);
}

// ---- Chebyshev coefficients via DCT-II -> ctf[k][16] f32 (k-major) ----
__global__ void k_cheb(const float* __restrict__ h1n, float* __restrict__ ctf) {
  int tid = blockIdx.x * 256 + threadIdx.x;          // 4096
  int d = tid >> 8, k = tid & 255;
  float s = 0.f;
  for (int j = 0; j < 16; ++j)
    s += h1n[j * 256 + k] * cosf(PI_F * (float)d * ((float)j + 0.5f) / 16.0f);
  ctf[k * 16 + d] = s * ((d == 0) ? (1.0f / 16.0f) : (2.0f / 16.0f));
}

// ---- P-gen: A'[b][s*16+d] = [T_hi | T_hi | T_lo], T_d = Cheb(2*min(y,1)-1) ----
__global__ void k_pgen(const float* __restrict__ y, unsigned short* __restrict__ Ps) {
  int n = blockIdx.x * 256 + threadIdx.x;            // 128000 exact
  float xv = 2.0f * fminf(y[n], 1.0f) - 1.0f;
  float T[16];
  T[0] = 1.0f; T[1] = xv;
#pragma unroll
  for (int d = 2; d < 16; ++d) T[d] = 2.0f * xv * T[d - 1] - T[d - 2];
  f32x4 t0 = {T[0], T[1], T[2], T[3]},   t1 = {T[4], T[5], T[6], T[7]};
  f32x4 t2 = {T[8], T[9], T[10], T[11]}, t3 = {T[12], T[13], T[14], T[15]};
  s16x8 h0v, l0v, h1v, l1v;
  split8(t0, t1, &h0v, &l0v);
  split8(t2, t3, &h1v, &l1v);
  int bb = n / S_, ss = n - bb * S_;
  unsigned short* base = Ps + (size_t)bb * KE + ss * 16;
  *(s16x8*)(base)         = h0v;  *(s16x8*)(base + 8)         = h1v;
  *(s16x8*)(base + 8000)  = h0v;  *(s16x8*)(base + 8008)      = h1v;
  *(s16x8*)(base + 16000) = l0v;  *(s16x8*)(base + 16008)     = l1v;
}

// ---- Q v3: pure-VALU streaming reduction. thread = one fc_w row (1 KB),
// walked in 8 bursts of 8 x f32x4 (back-to-back same-line loads, MSHR-merged).
// acc[16] in f32; c-table read with loop-uniform addresses (scalar/L1 hit).
// No LDS, no barriers, no MFMA. Writes B' = [Q_hi | Q_lo | Q_hi].
__global__ __launch_bounds__(256) void k_q(
    const float* __restrict__ W, const float* __restrict__ ctf,
    unsigned short* __restrict__ Qs) {
  int os = blockIdx.x * 256 + threadIdx.x;           // grid 977 -> 250112
  if (os >= 250000) return;
  const float* wp = W + (size_t)os * 256;
  f32x4 a0 = {0.f,0.f,0.f,0.f}, a1 = a0, a2 = a0, a3 = a0;
  for (int b8 = 0; b8 < 8; ++b8) {                   // 8 bursts of 128 B
    f32x4 wv[8];
#pragma unroll
    for (int i = 0; i < 8; ++i) wv[i] = *(const f32x4*)(wp + b8 * 32 + i * 4);
#pragma unroll
    for (int i = 0; i < 8; ++i) {
#pragma unroll
      for (int j = 0; j < 4; ++j) {
        const float* cp = ctf + (b8 * 32 + i * 4 + j) * 16;
        f32x4 c0 = *(const f32x4*)cp;
        f32x4 c1 = *(const f32x4*)(cp + 4);
        f32x4 c2 = *(const f32x4*)(cp + 8);
        f32x4 c3 = *(const f32x4*)(cp + 12);
        float wsc = wv[i][j];
        a0 += wsc * c0; a1 += wsc * c1; a2 += wsc * c2; a3 += wsc * c3;
      }
    }
  }
  int o = os / 500, s = os - o * 500;
  s16x8 hi01, lo01, hi23, lo23;
  split8(a0, a1, &hi01, &lo01);
  split8(a2, a3, &hi23, &lo23);
  unsigned short* qb = Qs + (size_t)o * KE + s * 16;
  *(s16x8*)(qb)          = hi01;  *(s16x8*)(qb + 8)     = hi23;
  *(s16x8*)(qb + 8000)   = lo01;  *(s16x8*)(qb + 8008)  = lo23;
  *(s16x8*)(qb + 16000)  = hi01;  *(s16x8*)(qb + 16008) = hi23;
}

// ---- final GEMM: pfc[ks] += A'(256xKE) . B'(500xKE)^T over ks-chunk of 960 ----
// grid 400 = ks(25) x bm(2) x bo(8); 4 waves, no LDS, no barriers.
__global__ __launch_bounds__(256) void k_fc(
    const unsigned short* __restrict__ Ps, const unsigned short* __restrict__ Qs,
    float* __restrict__ pfc) {
  const int blk = blockIdx.x;
  const int ks = blk % 25, rest = blk / 25;
  const int bm = rest & 1, bo = rest >> 1;
  const int lane = threadIdx.x & 63, nw = threadIdx.x >> 6;
  const int kbase = ks * 960;
  const int ob = bo * 64 + nw * 16 + (lane & 15);
  const int obc = ob > 499 ? 499 : ob;
  const unsigned short* bp = Qs + (size_t)obc * KE + kbase + (lane >> 4) * 8;
  const unsigned short* ap = Ps + (size_t)(bm * 128 + (lane & 15)) * KE + kbase + (lane >> 4) * 8;
  f32x4 acc[8] = {};
#pragma unroll 3
  for (int st = 0; st < 30; ++st) {
    s16x8 bf = *(const s16x8*)(bp + st * 32);
#pragma unroll
    for (int mf = 0; mf < 8; ++mf) {
      s16x8 af = *(const s16x8*)(ap + (size_t)mf * 16 * KE + st * 32);
      acc[mf] = __builtin_amdgcn_mfma_f32_16x16x32_bf16(af, bf, acc[mf], 0, 0, 0);
    }
  }
  const int col = bo * 64 + nw * 16 + (lane & 15);
  if (col < OUT_) {
    float* pp = pfc + (size_t)ks * 128000;
#pragma unroll
    for (int mf = 0; mf < 8; ++mf) {
#pragma unroll
      for (int r = 0; r < 4; ++r) {
        int row = bm * 128 + mf * 16 + (lane >> 4) * 4 + r;
        pp[row * OUT_ + col] = acc[mf][r];
      }
    }
  }
}

// ---- reduce: out[i] = fc_b[i%500] + sum_ks pfc[ks][i] ----
__global__ void k_red2(const float* __restrict__ pfc, const float* __restrict__ fcb,
                       float* __restrict__ out) {
  int i = blockIdx.x * 256 + threadIdx.x;            // 128000 exact
  int o = i % OUT_;
  float s = fcb[o];
#pragma unroll 5
  for (int ks = 0; ks < 25; ++ks) s += pfc[(size_t)ks * 128000 + i];
  out[i] = s;
}

extern "C" void kernel_launch(void* const* d_in, const int* in_sizes, int n_in,
                              void* d_out, int out_size, void* d_ws, size_t ws_size,
                              hipStream_t stream) {
  const float* x      = (const float*)d_in[0];
  const float* conv_w = (const float*)d_in[1];
  const float* conv_b = (const float*)d_in[2];
  const float* w_ih0  = (const float*)d_in[3];
  const float* b_ih0  = (const float*)d_in[4];
  const float* b_hh0  = (const float*)d_in[5];
  const float* w_ih1  = (const float*)d_in[6];
  const float* b_ih1  = (const float*)d_in[7];
  const float* b_hh1  = (const float*)d_in[8];
  const float* fc_w   = (const float*)d_in[9];
  const float* fc_b   = (const float*)d_in[10];
  float* out = (float*)d_out;

  char* ws = (char*)d_ws;
  float* y            = (float*)ws;                        // 512,000 B
  float* h0n          = (float*)(ws + 524288);             // 16,384 B
  float* h1n          = (float*)(ws + 540672);             // 16,384 B
  float* ctf          = (float*)(ws + 557056);             // 16,384 B
  unsigned short* Ps  = (unsigned short*)(ws + 1048576);   // 12,288,000 B
  unsigned short* Qs  = (unsigned short*)(ws + 14680064);  // 24,000,000 B
  float* pfc          = (float*)(ws + 41943040);           // 12,800,000 B

  k_conv<<<500, 256, 0, stream>>>(x, conv_w, conv_b, y);
  k_h0n<<<16, 256, 0, stream>>>(w_ih0, b_ih0, b_hh0, h0n);
  k_h1n<<<16, 256, 0, stream>>>(h0n, w_ih1, b_ih1, b_hh1, h1n);
  k_cheb<<<16, 256, 0, stream>>>(h1n, ctf);
  k_pgen<<<500, 256, 0, stream>>>(y, Ps);
  k_q<<<977, 256, 0, stream>>>(fc_w, ctf, Qs);
  k_fc<<<400, 256, 0, stream>>>(Ps, Qs, pfc);
  k_red2<<<500, 256, 0, stream>>>(pfc, fc_b, out);
}